// Round 2
// baseline (1222.551 us; speedup 1.0000x reference)
//
#include <hip/hip_runtime.h>

#define N_NODES 100000
#define N_EDGESV 1000000
#define N_REL 7
#define IN_CH 128
#define HID_CH 64
#define OUT_CH 2
#define NB 4
#define DI 32
#define DO 16
#define WSTRIDE 528  // 32*16 + 16 pad: bank(b-group) alternates by 16 -> 2-way alias (free)

// ---- order-preserving float<->uint encoding; 0 == "empty" sentinel ----
__device__ __forceinline__ unsigned encf(float f) {
    unsigned u = __float_as_uint(f);
    return u ^ ((u >> 31) ? 0xFFFFFFFFu : 0x80000000u);
}
__device__ __forceinline__ float decf(unsigned u) {
    return __uint_as_float((u >> 31) ? (u ^ 0x80000000u) : ~u);
}

// ---- layer-1 edge kernel: one wave per edge, lane = out channel ----
// buf index: (dst*relMul + (relFilter<0 ? r : 0)) * 64 + lane
__global__ __launch_bounds__(256, 2)
void edge1_kernel(const float* __restrict__ x, const int* __restrict__ ei,
                  const int* __restrict__ et, const float* __restrict__ W1,
                  unsigned* __restrict__ buf, int relMul, int relFilter)
{
    __shared__ float wl[N_REL * NB * WSTRIDE];  // 59136 B
    for (int idx = threadIdx.x; idx < N_REL * NB * DI * DO; idx += blockDim.x) {
        int j = idx & 15;
        int i = (idx >> 4) & 31;
        int rb = idx >> 9;
        wl[rb * WSTRIDE + i * 16 + j] = W1[idx];
    }
    __syncthreads();

    const int lane = threadIdx.x & 63;
    const int b = lane >> 4;
    const int wid = blockIdx.x * (blockDim.x >> 6) + (threadIdx.x >> 6);
    const int nw = gridDim.x * (blockDim.x >> 6);

    for (int e = wid; e < N_EDGESV; e += nw) {
        int r = et[e];
        if (relFilter >= 0 && r != relFilter) continue;
        int s = ei[e];
        int d = ei[N_EDGESV + e];
        const float4* xr = (const float4*)(x + (size_t)s * IN_CH) + (b << 3);
        const float* wr = &wl[(r * NB + b) * WSTRIDE + (lane & 15)];
        float acc = 0.f;
#pragma unroll
        for (int i4 = 0; i4 < 8; ++i4) {
            float4 xv = xr[i4];
            acc = fmaf(xv.x, wr[(i4 * 4 + 0) * 16], acc);
            acc = fmaf(xv.y, wr[(i4 * 4 + 1) * 16], acc);
            acc = fmaf(xv.z, wr[(i4 * 4 + 2) * 16], acc);
            acc = fmaf(xv.w, wr[(i4 * 4 + 3) * 16], acc);
        }
        int rr = (relFilter < 0) ? r : 0;
        atomicMax(buf + ((size_t)d * relMul + rr) * HID_CH + lane, encf(acc));
    }
}

// ---- finalize layer 1: h = [relu](x@root1 + bias1 + sum_r dec(buf)) ----
__global__ __launch_bounds__(256, 4)
void finalize1_kernel(const float* __restrict__ x, const float* __restrict__ root1,
                      const float* __restrict__ bias1, const unsigned* __restrict__ buf,
                      float* __restrict__ h, int nrel, int doRelu)
{
    __shared__ float rl[IN_CH * HID_CH];  // 32 KB
    for (int idx = threadIdx.x; idx < IN_CH * HID_CH; idx += blockDim.x)
        rl[idx] = root1[idx];
    __syncthreads();

    const int lane = threadIdx.x & 63;
    const int wid = blockIdx.x * (blockDim.x >> 6) + (threadIdx.x >> 6);
    const int nw = gridDim.x * (blockDim.x >> 6);

    for (int n = wid; n < N_NODES; n += nw) {
        const float4* xr = (const float4*)(x + (size_t)n * IN_CH);
        float acc = bias1[lane];
#pragma unroll 8
        for (int i4 = 0; i4 < 32; ++i4) {
            float4 xv = xr[i4];  // wave-uniform broadcast
            acc = fmaf(xv.x, rl[(i4 * 4 + 0) * HID_CH + lane], acc);
            acc = fmaf(xv.y, rl[(i4 * 4 + 1) * HID_CH + lane], acc);
            acc = fmaf(xv.z, rl[(i4 * 4 + 2) * HID_CH + lane], acc);
            acc = fmaf(xv.w, rl[(i4 * 4 + 3) * HID_CH + lane], acc);
        }
        for (int r = 0; r < nrel; ++r) {
            unsigned u = buf[((size_t)n * N_REL + r) * HID_CH + lane];
            if (u) acc += decf(u);
        }
        h[(size_t)n * HID_CH + lane] = doRelu ? fmaxf(acc, 0.f) : acc;
    }
}

// ---- path-B helper: h += dec(buf) elementwise, optional relu ----
__global__ __launch_bounds__(256)
void addmax_kernel(float* __restrict__ h, const unsigned* __restrict__ buf, int doRelu)
{
    const int total = N_NODES * HID_CH;
    for (int i = blockIdx.x * blockDim.x + threadIdx.x; i < total;
         i += gridDim.x * blockDim.x) {
        unsigned u = buf[i];
        float v = h[i];
        if (u) v += decf(u);
        if (doRelu) v = fmaxf(v, 0.f);
        h[i] = v;
    }
}

// ---- layer-2 edge kernel: one wave per edge, lane over hidden channels ----
__global__ __launch_bounds__(256)
void edge2_kernel(const float* __restrict__ h, const int* __restrict__ ei,
                  const int* __restrict__ et, const float* __restrict__ comp2,
                  const float* __restrict__ basis2, unsigned* __restrict__ buf2)
{
    __shared__ float w2[N_REL * HID_CH * OUT_CH];  // 896 floats
    for (int idx = threadIdx.x; idx < N_REL * HID_CH * OUT_CH; idx += blockDim.x) {
        int o = idx & 1;
        int i = (idx >> 1) & (HID_CH - 1);
        int r = idx >> 7;
        float v = 0.f;
#pragma unroll
        for (int bb = 0; bb < NB; ++bb)
            v += comp2[r * NB + bb] * basis2[(bb * HID_CH + i) * OUT_CH + o];
        w2[idx] = v;
    }
    __syncthreads();

    const int lane = threadIdx.x & 63;
    const int wid = blockIdx.x * (blockDim.x >> 6) + (threadIdx.x >> 6);
    const int nw = gridDim.x * (blockDim.x >> 6);
    const float2* w2v = (const float2*)w2;

    for (int e = wid; e < N_EDGESV; e += nw) {
        int r = et[e];
        int s = ei[e];
        int d = ei[N_EDGESV + e];
        float hv = h[(size_t)s * HID_CH + lane];
        float2 w = w2v[r * HID_CH + lane];
        float m0 = hv * w.x;
        float m1 = hv * w.y;
#pragma unroll
        for (int off = 32; off > 0; off >>= 1) {
            m0 += __shfl_down(m0, off);
            m1 += __shfl_down(m1, off);
        }
        if (lane == 0) {  // lane 0 holds the FULL sums of both m0 and m1
            unsigned* p = buf2 + ((size_t)d * N_REL + r) * OUT_CH;
            atomicMax(p + 0, encf(m0));
            atomicMax(p + 1, encf(m1));
        }
    }
}

// ---- finalize layer 2: out = h@root2 + bias2 + sum_r dec(buf2) ----
// NOTE: shfl_down tree leaves the full sum ONLY in lane 0 — lane 0 writes both
// output channels (lane 1's m1 is a partial sum; that was the round-1 bug).
__global__ __launch_bounds__(256)
void finalize2_kernel(const float* __restrict__ h, const float* __restrict__ root2,
                      const float* __restrict__ bias2, const unsigned* __restrict__ buf2,
                      float* __restrict__ out)
{
    const int lane = threadIdx.x & 63;
    const int wid = blockIdx.x * (blockDim.x >> 6) + (threadIdx.x >> 6);
    const int nw = gridDim.x * (blockDim.x >> 6);
    const float r0 = root2[lane * 2 + 0];
    const float r1 = root2[lane * 2 + 1];

    for (int n = wid; n < N_NODES; n += nw) {
        float hv = h[(size_t)n * HID_CH + lane];
        float m0 = hv * r0;
        float m1 = hv * r1;
#pragma unroll
        for (int off = 32; off > 0; off >>= 1) {
            m0 += __shfl_down(m0, off);
            m1 += __shfl_down(m1, off);
        }
        if (lane == 0) {
            float a0 = m0 + bias2[0];
            float a1 = m1 + bias2[1];
            for (int r = 0; r < N_REL; ++r) {
                unsigned u0 = buf2[((size_t)n * N_REL + r) * OUT_CH + 0];
                unsigned u1 = buf2[((size_t)n * N_REL + r) * OUT_CH + 1];
                if (u0) a0 += decf(u0);
                if (u1) a1 += decf(u1);
            }
            out[(size_t)n * OUT_CH + 0] = a0;
            out[(size_t)n * OUT_CH + 1] = a1;
        }
    }
}

extern "C" void kernel_launch(void* const* d_in, const int* in_sizes, int n_in,
                              void* d_out, int out_size, void* d_ws, size_t ws_size,
                              hipStream_t stream)
{
    const float* x      = (const float*)d_in[0];
    const int*   ei     = (const int*)d_in[1];
    const int*   et     = (const int*)d_in[2];
    const float* W1     = (const float*)d_in[3];
    const float* root1  = (const float*)d_in[4];
    const float* bias1  = (const float*)d_in[5];
    const float* comp2  = (const float*)d_in[6];
    const float* basis2 = (const float*)d_in[7];
    const float* root2  = (const float*)d_in[8];
    const float* bias2  = (const float*)d_in[9];
    float* out = (float*)d_out;

    const size_t sz_buf1 = (size_t)N_NODES * N_REL * HID_CH * sizeof(unsigned); // 179.2 MB
    const size_t sz_buf2 = (size_t)N_NODES * N_REL * OUT_CH * sizeof(unsigned); //   5.6 MB
    const size_t sz_h    = (size_t)N_NODES * HID_CH * sizeof(float);            //  25.6 MB
    const size_t sz_bufB = (size_t)N_NODES * HID_CH * sizeof(unsigned);         //  25.6 MB

    char* ws = (char*)d_ws;

    if (ws_size >= sz_buf1 + sz_buf2 + sz_h) {
        // Path A: single-pass, per-(node, relation, channel) max buffers
        unsigned* buf1 = (unsigned*)ws;
        unsigned* buf2 = (unsigned*)(ws + sz_buf1);
        float*    h    = (float*)(ws + sz_buf1 + sz_buf2);

        hipMemsetAsync(buf1, 0, sz_buf1 + sz_buf2, stream);
        edge1_kernel<<<1024, 256, 0, stream>>>(x, ei, et, W1, buf1, N_REL, -1);
        finalize1_kernel<<<1024, 256, 0, stream>>>(x, root1, bias1, buf1, h, N_REL, 1);
        edge2_kernel<<<2048, 256, 0, stream>>>(h, ei, et, comp2, basis2, buf2);
        finalize2_kernel<<<1024, 256, 0, stream>>>(h, root2, bias2, buf2, out);
    } else {
        // Path B: loop relations for layer 1, reuse one [N,64] buffer
        unsigned* buf  = (unsigned*)ws;
        unsigned* buf2 = (unsigned*)(ws + sz_bufB);
        float*    h    = (float*)(ws + sz_bufB + sz_buf2);

        hipMemsetAsync(buf, 0, sz_bufB + sz_buf2, stream);
        finalize1_kernel<<<1024, 256, 0, stream>>>(x, root1, bias1, nullptr, h, 0, 0);
        for (int r = 0; r < N_REL; ++r) {
            if (r > 0) hipMemsetAsync(buf, 0, sz_bufB, stream);
            edge1_kernel<<<1024, 256, 0, stream>>>(x, ei, et, W1, buf, 1, r);
            addmax_kernel<<<2048, 256, 0, stream>>>(h, buf, (r == N_REL - 1) ? 1 : 0);
        }
        edge2_kernel<<<2048, 256, 0, stream>>>(h, ei, et, comp2, basis2, buf2);
        finalize2_kernel<<<1024, 256, 0, stream>>>(h, root2, bias2, buf2, out);
    }
}

// Round 3
// 1090.874 us; speedup vs baseline: 1.1207x; 1.1207x over previous
//
#include <hip/hip_runtime.h>

#define N_NODES 100000
#define N_EDGESV 1000000
#define N_REL 7
#define IN_CH 128
#define HID_CH 64
#define OUT_CH 2
#define NB 4
#define DI 32
#define DO 16
#define WSTRIDE 528   // 32*16+16 pad: b-groups alias banks 2-way (free per m136)
#define SRC_MASK 131071  // 2^17-1; N_NODES < 2^17, rel in bits [17..20)
#define SCAN_CHUNK 1024
#define NCHUNKS ((N_NODES + SCAN_CHUNK - 1) / SCAN_CHUNK)  // 98

// ================= CSR build =================
__global__ void hist_kernel(const int* __restrict__ ei, int* __restrict__ deg) {
    int e = blockIdx.x * blockDim.x + threadIdx.x;
    if (e < N_EDGESV) atomicAdd(&deg[ei[N_EDGESV + e]], 1);
}

// 256 threads x 4 elements = 1024/chunk; inclusive scan within chunk -> off[i+1]
__global__ void scan1_kernel(const int* __restrict__ deg, int* __restrict__ off,
                             int* __restrict__ sums) {
    __shared__ int lds[256];
    const int tid = threadIdx.x;
    const int base = blockIdx.x * SCAN_CHUNK + tid * 4;
    int v0 = (base + 0 < N_NODES) ? deg[base + 0] : 0;
    int v1 = (base + 1 < N_NODES) ? deg[base + 1] : 0;
    int v2 = (base + 2 < N_NODES) ? deg[base + 2] : 0;
    int v3 = (base + 3 < N_NODES) ? deg[base + 3] : 0;
    int t0 = v0, t1 = v0 + v1, t2 = t1 + v2, t3 = t2 + v3;
    lds[tid] = t3;
    __syncthreads();
    for (int d = 1; d < 256; d <<= 1) {
        int t = (tid >= d) ? lds[tid - d] : 0;
        __syncthreads();
        if (tid >= d) lds[tid] += t;
        __syncthreads();
    }
    int excl = lds[tid] - t3;
    if (base + 0 < N_NODES) off[base + 1] = excl + t0;
    if (base + 1 < N_NODES) off[base + 2] = excl + t1;
    if (base + 2 < N_NODES) off[base + 3] = excl + t2;
    if (base + 3 < N_NODES) off[base + 4] = excl + t3;
    if (tid == 255) sums[blockIdx.x] = lds[255];
}

__global__ void scan2_kernel(int* __restrict__ sums) {
    __shared__ int lds[128];
    int t = threadIdx.x;
    lds[t] = (t < NCHUNKS) ? sums[t] : 0;
    __syncthreads();
    for (int d = 1; d < 128; d <<= 1) {
        int v = (t >= d) ? lds[t - d] : 0;
        __syncthreads();
        if (t >= d) lds[t] += v;
        __syncthreads();
    }
    if (t < NCHUNKS) sums[t] = lds[t];
}

__global__ void scan3_kernel(int* __restrict__ off, const int* __restrict__ sums,
                             int* __restrict__ cursor) {
    int i = blockIdx.x * blockDim.x + threadIdx.x;
    if (i == 0) { off[0] = 0; cursor[0] = 0; }
    if (i < N_NODES) {
        int chunk = i / SCAN_CHUNK;
        int v = off[i + 1] + ((chunk > 0) ? sums[chunk - 1] : 0);
        off[i + 1] = v;
        cursor[i + 1] = v;
    }
}

__global__ void scatter_kernel(const int* __restrict__ ei, const int* __restrict__ et,
                               int* __restrict__ cursor, int* __restrict__ packed) {
    int e = blockIdx.x * blockDim.x + threadIdx.x;
    if (e < N_EDGESV) {
        int d = ei[N_EDGESV + e];
        int pos = atomicAdd(&cursor[d], 1);
        packed[pos] = ei[e] | (et[e] << 17);
    }
}

// ================= hroot: h = x@root1 + bias1 (no relu yet) =================
__global__ __launch_bounds__(256, 4)
void rootmm_kernel(const float* __restrict__ x, const float* __restrict__ root1,
                   const float* __restrict__ bias1, float* __restrict__ h)
{
    __shared__ float rl[IN_CH * HID_CH];  // 32 KB
    for (int idx = threadIdx.x; idx < IN_CH * HID_CH; idx += blockDim.x)
        rl[idx] = root1[idx];
    __syncthreads();

    const int lane = threadIdx.x & 63;
    const int wid = blockIdx.x * (blockDim.x >> 6) + (threadIdx.x >> 6);
    const int nw = gridDim.x * (blockDim.x >> 6);

    for (int n = wid; n < N_NODES; n += nw) {
        const float4* xr = (const float4*)(x + ((size_t)n << 7));
        float acc = bias1[lane];
#pragma unroll 8
        for (int i4 = 0; i4 < 32; ++i4) {
            float4 xv = xr[i4];
            acc = fmaf(xv.x, rl[(i4 * 4 + 0) * HID_CH + lane], acc);
            acc = fmaf(xv.y, rl[(i4 * 4 + 1) * HID_CH + lane], acc);
            acc = fmaf(xv.z, rl[(i4 * 4 + 2) * HID_CH + lane], acc);
            acc = fmaf(xv.w, rl[(i4 * 4 + 3) * HID_CH + lane], acc);
        }
        h[((size_t)n << 6) + lane] = acc;
    }
}

// ===== layer-1 aggregation: wave per node, per-rel max kept in registers =====
// h := relu(h + sum_r max_{e in rel r} msg) ; no atomics, no big buffers.
__global__ __launch_bounds__(512, 4)
void agg1_kernel(const float* __restrict__ x, const int* __restrict__ off,
                 const int* __restrict__ packed, const float* __restrict__ W1,
                 float* __restrict__ h)
{
    __shared__ float wl[N_REL * NB * WSTRIDE];  // 59136 B -> 2x512thr blocks/CU
    for (int idx = threadIdx.x; idx < N_REL * NB * DI * DO; idx += blockDim.x) {
        int j = idx & 15;
        int i = (idx >> 4) & 31;
        int rb = idx >> 9;
        wl[rb * WSTRIDE + i * 16 + j] = W1[idx];
    }
    __syncthreads();

    const int lane = threadIdx.x & 63;
    const int b = lane >> 4;
    const int j = lane & 15;
    const int wid = blockIdx.x * (blockDim.x >> 6) + (threadIdx.x >> 6);
    const int nw = gridDim.x * (blockDim.x >> 6);

    for (int n = wid; n < N_NODES; n += nw) {
        const int st = off[n], en = off[n + 1];
        float a0 = 0.f, a1 = 0.f, a2 = 0.f, a3 = 0.f, a4 = 0.f, a5 = 0.f, a6 = 0.f;
        int seen = 0;
        int pk = (st < en) ? packed[st] : 0;
        for (int p = st; p < en; ++p) {
            int pk_next = (p + 1 < en) ? packed[p + 1] : 0;  // prefetch
            int s = pk & SRC_MASK;
            int r = pk >> 17;
            const float4* xr = (const float4*)(x + ((size_t)s << 7)) + (b << 3);
            const float* wr = &wl[(r * NB + b) * WSTRIDE + j];
            float m = 0.f;
#pragma unroll
            for (int i4 = 0; i4 < 8; ++i4) {
                float4 xv = xr[i4];
                m = fmaf(xv.x, wr[(i4 * 4 + 0) * 16], m);
                m = fmaf(xv.y, wr[(i4 * 4 + 1) * 16], m);
                m = fmaf(xv.z, wr[(i4 * 4 + 2) * 16], m);
                m = fmaf(xv.w, wr[(i4 * 4 + 3) * 16], m);
            }
            // first-seen initializes, afterwards max (branchless selects)
            a0 = (r == 0) ? ((seen & 1)   ? fmaxf(a0, m) : m) : a0;
            a1 = (r == 1) ? ((seen & 2)   ? fmaxf(a1, m) : m) : a1;
            a2 = (r == 2) ? ((seen & 4)   ? fmaxf(a2, m) : m) : a2;
            a3 = (r == 3) ? ((seen & 8)   ? fmaxf(a3, m) : m) : a3;
            a4 = (r == 4) ? ((seen & 16)  ? fmaxf(a4, m) : m) : a4;
            a5 = (r == 5) ? ((seen & 32)  ? fmaxf(a5, m) : m) : a5;
            a6 = (r == 6) ? ((seen & 64)  ? fmaxf(a6, m) : m) : a6;
            seen |= 1 << r;
            pk = pk_next;
        }
        float add = 0.f;
        if (seen & 1)  add += a0;
        if (seen & 2)  add += a1;
        if (seen & 4)  add += a2;
        if (seen & 8)  add += a3;
        if (seen & 16) add += a4;
        if (seen & 32) add += a5;
        if (seen & 64) add += a6;
        size_t hi = ((size_t)n << 6) + lane;
        h[hi] = fmaxf(h[hi] + add, 0.f);
    }
}

// ===== layer-2: wave per node; butterfly-reduce per edge; regs for per-rel max =====
__global__ __launch_bounds__(256, 4)
void agg2_kernel(const float* __restrict__ h, const int* __restrict__ off,
                 const int* __restrict__ packed, const float* __restrict__ comp2,
                 const float* __restrict__ basis2, const float* __restrict__ root2,
                 const float* __restrict__ bias2, float* __restrict__ out)
{
    __shared__ float w2[N_REL * 2 * HID_CH];  // [r][o][i] layout: stride-1 lane reads
    for (int idx = threadIdx.x; idx < N_REL * 2 * HID_CH; idx += blockDim.x) {
        int i = idx & 63;
        int o = (idx >> 6) & 1;
        int r = idx >> 7;
        float v = 0.f;
#pragma unroll
        for (int bb = 0; bb < NB; ++bb)
            v += comp2[r * NB + bb] * basis2[(bb * HID_CH + i) * OUT_CH + o];
        w2[idx] = v;
    }
    __syncthreads();

    const int lane = threadIdx.x & 63;
    const int wid = blockIdx.x * (blockDim.x >> 6) + (threadIdx.x >> 6);
    const int nw = gridDim.x * (blockDim.x >> 6);
    const float r0 = root2[lane * 2 + 0];
    const float r1 = root2[lane * 2 + 1];
    const float b20 = bias2[0], b21 = bias2[1];

    for (int n = wid; n < N_NODES; n += nw) {
        const int st = off[n], en = off[n + 1];
        float a0x=0,a1x=0,a2x=0,a3x=0,a4x=0,a5x=0,a6x=0;
        float a0y=0,a1y=0,a2y=0,a3y=0,a4y=0,a5y=0,a6y=0;
        int seen = 0;
        for (int p = st; p < en; ++p) {
            int pk = packed[p];
            int s = pk & SRC_MASK;
            int r = pk >> 17;
            float hv = h[((size_t)s << 6) + lane];
            float v0 = hv * w2[r * 128 + lane];
            float v1 = hv * w2[r * 128 + 64 + lane];
#pragma unroll
            for (int o = 32; o > 0; o >>= 1) {  // xor butterfly: ALL lanes get totals
                v0 += __shfl_xor(v0, o);
                v1 += __shfl_xor(v1, o);
            }
            a0x = (r==0) ? ((seen&1) ? fmaxf(a0x,v0) : v0) : a0x;
            a0y = (r==0) ? ((seen&1) ? fmaxf(a0y,v1) : v1) : a0y;
            a1x = (r==1) ? ((seen&2) ? fmaxf(a1x,v0) : v0) : a1x;
            a1y = (r==1) ? ((seen&2) ? fmaxf(a1y,v1) : v1) : a1y;
            a2x = (r==2) ? ((seen&4) ? fmaxf(a2x,v0) : v0) : a2x;
            a2y = (r==2) ? ((seen&4) ? fmaxf(a2y,v1) : v1) : a2y;
            a3x = (r==3) ? ((seen&8) ? fmaxf(a3x,v0) : v0) : a3x;
            a3y = (r==3) ? ((seen&8) ? fmaxf(a3y,v1) : v1) : a3y;
            a4x = (r==4) ? ((seen&16)? fmaxf(a4x,v0) : v0) : a4x;
            a4y = (r==4) ? ((seen&16)? fmaxf(a4y,v1) : v1) : a4y;
            a5x = (r==5) ? ((seen&32)? fmaxf(a5x,v0) : v0) : a5x;
            a5y = (r==5) ? ((seen&32)? fmaxf(a5y,v1) : v1) : a5y;
            a6x = (r==6) ? ((seen&64)? fmaxf(a6x,v0) : v0) : a6x;
            a6y = (r==6) ? ((seen&64)? fmaxf(a6y,v1) : v1) : a6y;
            seen |= 1 << r;
        }
        // self term: h[n]@root2
        float hv = h[((size_t)n << 6) + lane];
        float u0 = hv * r0;
        float u1 = hv * r1;
#pragma unroll
        for (int o = 32; o > 0; o >>= 1) {
            u0 += __shfl_xor(u0, o);
            u1 += __shfl_xor(u1, o);
        }
        float o0 = u0 + b20, o1 = u1 + b21;
        if (seen & 1)  { o0 += a0x; o1 += a0y; }
        if (seen & 2)  { o0 += a1x; o1 += a1y; }
        if (seen & 4)  { o0 += a2x; o1 += a2y; }
        if (seen & 8)  { o0 += a3x; o1 += a3y; }
        if (seen & 16) { o0 += a4x; o1 += a4y; }
        if (seen & 32) { o0 += a5x; o1 += a5y; }
        if (seen & 64) { o0 += a6x; o1 += a6y; }
        if (lane == 0) {
            out[(size_t)n * OUT_CH + 0] = o0;
            out[(size_t)n * OUT_CH + 1] = o1;
        }
    }
}

extern "C" void kernel_launch(void* const* d_in, const int* in_sizes, int n_in,
                              void* d_out, int out_size, void* d_ws, size_t ws_size,
                              hipStream_t stream)
{
    const float* x      = (const float*)d_in[0];
    const int*   ei     = (const int*)d_in[1];
    const int*   et     = (const int*)d_in[2];
    const float* W1     = (const float*)d_in[3];
    const float* root1  = (const float*)d_in[4];
    const float* bias1  = (const float*)d_in[5];
    const float* comp2  = (const float*)d_in[6];
    const float* basis2 = (const float*)d_in[7];
    const float* root2  = (const float*)d_in[8];
    const float* bias2  = (const float*)d_in[9];
    float* out = (float*)d_out;

    // workspace carve-up (~31 MB total)
    char* ws = (char*)d_ws;
    size_t o = 0;
    auto carve = [&](size_t bytes) { char* p = ws + o; o += (bytes + 255) & ~(size_t)255; return p; };
    int*   deg    = (int*)carve(sizeof(int) * N_NODES);
    int*   off    = (int*)carve(sizeof(int) * (N_NODES + 1));
    int*   cursor = (int*)carve(sizeof(int) * (N_NODES + 1));
    int*   sums   = (int*)carve(sizeof(int) * 128);
    int*   packed = (int*)carve(sizeof(int) * N_EDGESV);
    float* h      = (float*)carve(sizeof(float) * (size_t)N_NODES * HID_CH);

    // ---- CSR build ----
    hipMemsetAsync(deg, 0, sizeof(int) * N_NODES, stream);
    hist_kernel<<<(N_EDGESV + 255) / 256, 256, 0, stream>>>(ei, deg);
    scan1_kernel<<<NCHUNKS, 256, 0, stream>>>(deg, off, sums);
    scan2_kernel<<<1, 128, 0, stream>>>(sums);
    scan3_kernel<<<(N_NODES + 255) / 256, 256, 0, stream>>>(off, sums, cursor);
    scatter_kernel<<<(N_EDGESV + 255) / 256, 256, 0, stream>>>(ei, et, cursor, packed);

    // ---- layer 1 ----
    rootmm_kernel<<<1024, 256, 0, stream>>>(x, root1, bias1, h);
    agg1_kernel<<<(N_NODES + 7) / 8, 512, 0, stream>>>(x, off, packed, W1, h);

    // ---- layer 2 ----
    agg2_kernel<<<(N_NODES + 3) / 4, 256, 0, stream>>>(h, off, packed, comp2, basis2,
                                                       root2, bias2, out);
}

// Round 4
// 616.996 us; speedup vs baseline: 1.9815x; 1.7680x over previous
//
#include <hip/hip_runtime.h>
#include <hip/hip_fp16.h>

#define N_NODES 100000
#define N_EDGESV 1000000
#define N_REL 7
#define IN_CH 128
#define HID_CH 64
#define OUT_CH 2
#define NB 4
#define DI 32
#define DO 16
#define WSTRIDE 528   // 32*16+16 pad: b-groups alias banks 2-way (free per m136)
#define SRC_MASK 131071  // 2^17-1; src in bits [0,17), rel in [17,20)
#define SCAN_CHUNK 1024
#define NCHUNKS ((N_NODES + SCAN_CHUNK - 1) / SCAN_CHUNK)  // 98
#define NEGI -3.0e38f
#define NEGTEST -1.0e38f

// ================= CSR build =================
__global__ void hist_kernel(const int* __restrict__ ei, int* __restrict__ deg) {
    int e = blockIdx.x * blockDim.x + threadIdx.x;
    if (e < N_EDGESV) atomicAdd(&deg[ei[N_EDGESV + e]], 1);
}

__global__ void scan1_kernel(const int* __restrict__ deg, int* __restrict__ off,
                             int* __restrict__ sums) {
    __shared__ int lds[256];
    const int tid = threadIdx.x;
    const int base = blockIdx.x * SCAN_CHUNK + tid * 4;
    int v0 = (base + 0 < N_NODES) ? deg[base + 0] : 0;
    int v1 = (base + 1 < N_NODES) ? deg[base + 1] : 0;
    int v2 = (base + 2 < N_NODES) ? deg[base + 2] : 0;
    int v3 = (base + 3 < N_NODES) ? deg[base + 3] : 0;
    int t0 = v0, t1 = v0 + v1, t2 = t1 + v2, t3 = t2 + v3;
    lds[tid] = t3;
    __syncthreads();
    for (int d = 1; d < 256; d <<= 1) {
        int t = (tid >= d) ? lds[tid - d] : 0;
        __syncthreads();
        if (tid >= d) lds[tid] += t;
        __syncthreads();
    }
    int excl = lds[tid] - t3;
    if (base + 0 < N_NODES) off[base + 1] = excl + t0;
    if (base + 1 < N_NODES) off[base + 2] = excl + t1;
    if (base + 2 < N_NODES) off[base + 3] = excl + t2;
    if (base + 3 < N_NODES) off[base + 4] = excl + t3;
    if (tid == 255) sums[blockIdx.x] = lds[255];
}

__global__ void scan2_kernel(int* __restrict__ sums) {
    __shared__ int lds[128];
    int t = threadIdx.x;
    lds[t] = (t < NCHUNKS) ? sums[t] : 0;
    __syncthreads();
    for (int d = 1; d < 128; d <<= 1) {
        int v = (t >= d) ? lds[t - d] : 0;
        __syncthreads();
        if (t >= d) lds[t] += v;
        __syncthreads();
    }
    if (t < NCHUNKS) sums[t] = lds[t];
}

__global__ void scan3_kernel(int* __restrict__ off, const int* __restrict__ sums,
                             int* __restrict__ cursor) {
    int i = blockIdx.x * blockDim.x + threadIdx.x;
    if (i == 0) { off[0] = 0; cursor[0] = 0; }
    if (i < N_NODES) {
        int chunk = i / SCAN_CHUNK;
        int v = off[i + 1] + ((chunk > 0) ? sums[chunk - 1] : 0);
        off[i + 1] = v;
        cursor[i + 1] = v;
    }
}

__global__ void scatter_kernel(const int* __restrict__ ei, const int* __restrict__ et,
                               int* __restrict__ cursor, int* __restrict__ packed) {
    int e = blockIdx.x * blockDim.x + threadIdx.x;
    if (e < N_EDGESV) {
        int d = ei[N_EDGESV + e];
        int pos = atomicAdd(&cursor[d], 1);
        packed[pos] = ei[e] | (et[e] << 17);
    }
}

// ========== hroot = x@root1 + bias1 (fp32, [N][64]) ==========
__global__ __launch_bounds__(256, 4)
void rootmm_kernel(const float* __restrict__ x, const float* __restrict__ root1,
                   const float* __restrict__ bias1, float* __restrict__ hroot)
{
    __shared__ float rl[IN_CH * HID_CH];  // 32 KB
    for (int idx = threadIdx.x; idx < IN_CH * HID_CH; idx += blockDim.x)
        rl[idx] = root1[idx];
    __syncthreads();

    const int lane = threadIdx.x & 63;
    const int wid = blockIdx.x * (blockDim.x >> 6) + (threadIdx.x >> 6);
    const int nw = gridDim.x * (blockDim.x >> 6);

    for (int n = wid; n < N_NODES; n += nw) {
        const float4* xr = (const float4*)(x + ((size_t)n << 7));
        float acc = bias1[lane];
#pragma unroll 8
        for (int i4 = 0; i4 < 32; ++i4) {
            float4 xv = xr[i4];  // wave-uniform broadcast
            acc = fmaf(xv.x, rl[(i4 * 4 + 0) * HID_CH + lane], acc);
            acc = fmaf(xv.y, rl[(i4 * 4 + 1) * HID_CH + lane], acc);
            acc = fmaf(xv.z, rl[(i4 * 4 + 2) * HID_CH + lane], acc);
            acc = fmaf(xv.w, rl[(i4 * 4 + 3) * HID_CH + lane], acc);
        }
        hroot[((size_t)n << 6) + lane] = acc;
    }
}

// ========== pre1: msg1[n][r][c] = (x[n] block-diag) @ W1[r], fp16 ==========
__global__ __launch_bounds__(256)
void pre1_kernel(const float* __restrict__ x, const float* __restrict__ W1,
                 __half* __restrict__ msg1)
{
    __shared__ float wl[N_REL * NB * WSTRIDE];  // 59136 B
    for (int idx = threadIdx.x; idx < N_REL * NB * DI * DO; idx += blockDim.x) {
        int j = idx & 15;
        int i = (idx >> 4) & 31;
        int rb = idx >> 9;
        wl[rb * WSTRIDE + i * 16 + j] = W1[idx];
    }
    __syncthreads();

    const int lane = threadIdx.x & 63;
    const int b = lane >> 4;
    const int j = lane & 15;
    const int wid = blockIdx.x * (blockDim.x >> 6) + (threadIdx.x >> 6);
    const int nw = gridDim.x * (blockDim.x >> 6);

    for (int n = wid; n < N_NODES; n += nw) {
        const float4* xr = (const float4*)(x + ((size_t)n << 7)) + (b << 3);
        float4 xv[8];
#pragma unroll
        for (int i4 = 0; i4 < 8; ++i4) xv[i4] = xr[i4];  // keep x block in regs
        __half* mrow = msg1 + (size_t)n * (N_REL * HID_CH) + lane;
#pragma unroll
        for (int r = 0; r < N_REL; ++r) {
            const float* wr = &wl[(r * NB + b) * WSTRIDE + j];
            float m = 0.f;
#pragma unroll
            for (int i4 = 0; i4 < 8; ++i4) {
                m = fmaf(xv[i4].x, wr[(i4 * 4 + 0) * 16], m);
                m = fmaf(xv[i4].y, wr[(i4 * 4 + 1) * 16], m);
                m = fmaf(xv[i4].z, wr[(i4 * 4 + 2) * 16], m);
                m = fmaf(xv[i4].w, wr[(i4 * 4 + 3) * 16], m);
            }
            mrow[r * HID_CH] = __float2half(m);  // 64x2B coalesced per r
        }
    }
}

// ========== agg1: wave/node; max fp16 msgs; fuse relu + msg2 build ==========
// msg2[n][k][2]: k=0..6 per-rel layer-2 message h[n]@W2[k]; k=7 self h[n]@root2+bias2
__global__ __launch_bounds__(256, 6)
void agg1_kernel(const __half* __restrict__ msg1, const float* __restrict__ hroot,
                 const int* __restrict__ off, const int* __restrict__ packed,
                 const float* __restrict__ comp2, const float* __restrict__ basis2,
                 const float* __restrict__ root2, const float* __restrict__ bias2,
                 float* __restrict__ msg2)
{
    __shared__ float w2[N_REL * 2 * HID_CH];  // [r][o][i], 3.5 KB
    for (int idx = threadIdx.x; idx < N_REL * 2 * HID_CH; idx += blockDim.x) {
        int i = idx & 63;
        int o = (idx >> 6) & 1;
        int r = idx >> 7;
        float v = 0.f;
#pragma unroll
        for (int bb = 0; bb < NB; ++bb)
            v += comp2[r * NB + bb] * basis2[(bb * HID_CH + i) * OUT_CH + o];
        w2[idx] = v;
    }
    __syncthreads();

    const int lane = threadIdx.x & 63;
    const int n = blockIdx.x * (blockDim.x >> 6) + (threadIdx.x >> 6);
    if (n >= N_NODES) return;

    const int st = off[n], en = off[n + 1];
    float a0 = NEGI, a1 = NEGI, a2 = NEGI, a3 = NEGI, a4 = NEGI, a5 = NEGI, a6 = NEGI;

    int p = st;
    for (; p + 1 < en; p += 2) {  // 2 independent gathers in flight
        int pk0 = packed[p];
        int pk1 = packed[p + 1];
        int r0 = pk0 >> 17, r1 = pk1 >> 17;
        float v0 = __half2float(msg1[(size_t)(pk0 & SRC_MASK) * (N_REL * HID_CH) + (r0 << 6) + lane]);
        float v1 = __half2float(msg1[(size_t)(pk1 & SRC_MASK) * (N_REL * HID_CH) + (r1 << 6) + lane]);
        a0 = fmaxf(a0, (r0 == 0) ? v0 : NEGI); a0 = fmaxf(a0, (r1 == 0) ? v1 : NEGI);
        a1 = fmaxf(a1, (r0 == 1) ? v0 : NEGI); a1 = fmaxf(a1, (r1 == 1) ? v1 : NEGI);
        a2 = fmaxf(a2, (r0 == 2) ? v0 : NEGI); a2 = fmaxf(a2, (r1 == 2) ? v1 : NEGI);
        a3 = fmaxf(a3, (r0 == 3) ? v0 : NEGI); a3 = fmaxf(a3, (r1 == 3) ? v1 : NEGI);
        a4 = fmaxf(a4, (r0 == 4) ? v0 : NEGI); a4 = fmaxf(a4, (r1 == 4) ? v1 : NEGI);
        a5 = fmaxf(a5, (r0 == 5) ? v0 : NEGI); a5 = fmaxf(a5, (r1 == 5) ? v1 : NEGI);
        a6 = fmaxf(a6, (r0 == 6) ? v0 : NEGI); a6 = fmaxf(a6, (r1 == 6) ? v1 : NEGI);
    }
    if (p < en) {
        int pk0 = packed[p];
        int r0 = pk0 >> 17;
        float v0 = __half2float(msg1[(size_t)(pk0 & SRC_MASK) * (N_REL * HID_CH) + (r0 << 6) + lane]);
        a0 = fmaxf(a0, (r0 == 0) ? v0 : NEGI);
        a1 = fmaxf(a1, (r0 == 1) ? v0 : NEGI);
        a2 = fmaxf(a2, (r0 == 2) ? v0 : NEGI);
        a3 = fmaxf(a3, (r0 == 3) ? v0 : NEGI);
        a4 = fmaxf(a4, (r0 == 4) ? v0 : NEGI);
        a5 = fmaxf(a5, (r0 == 5) ? v0 : NEGI);
        a6 = fmaxf(a6, (r0 == 6) ? v0 : NEGI);
    }
    float add = 0.f;
    add += (a0 > NEGTEST) ? a0 : 0.f;
    add += (a1 > NEGTEST) ? a1 : 0.f;
    add += (a2 > NEGTEST) ? a2 : 0.f;
    add += (a3 > NEGTEST) ? a3 : 0.f;
    add += (a4 > NEGTEST) ? a4 : 0.f;
    add += (a5 > NEGTEST) ? a5 : 0.f;
    add += (a6 > NEGTEST) ? a6 : 0.f;

    const float h = fmaxf(hroot[((size_t)n << 6) + lane] + add, 0.f);

    // ---- layer-2 message precompute: 14 dot-products + self term ----
    float o[16];
#pragma unroll
    for (int r = 0; r < N_REL; ++r) {
        float t0 = h * w2[r * 128 + lane];
        float t1 = h * w2[r * 128 + 64 + lane];
#pragma unroll
        for (int s = 32; s > 0; s >>= 1) {  // xor butterfly: all lanes get totals
            t0 += __shfl_xor(t0, s);
            t1 += __shfl_xor(t1, s);
        }
        o[r * 2] = t0;
        o[r * 2 + 1] = t1;
    }
    {
        float u0 = h * root2[lane * 2 + 0];
        float u1 = h * root2[lane * 2 + 1];
#pragma unroll
        for (int s = 32; s > 0; s >>= 1) {
            u0 += __shfl_xor(u0, s);
            u1 += __shfl_xor(u1, s);
        }
        o[14] = u0 + bias2[0];
        o[15] = u1 + bias2[1];
    }
    if (lane == 0) {
        float4* dst = (float4*)(msg2 + (size_t)n * 16);
        dst[0] = make_float4(o[0], o[1], o[2], o[3]);
        dst[1] = make_float4(o[4], o[5], o[6], o[7]);
        dst[2] = make_float4(o[8], o[9], o[10], o[11]);
        dst[3] = make_float4(o[12], o[13], o[14], o[15]);
    }
}

// ========== agg2: thread/node; per-edge float2 load + max from msg2 ==========
__global__ __launch_bounds__(256)
void agg2_kernel(const float* __restrict__ msg2, const int* __restrict__ off,
                 const int* __restrict__ packed, float* __restrict__ out)
{
    const int n = blockIdx.x * blockDim.x + threadIdx.x;
    if (n >= N_NODES) return;
    const int st = off[n], en = off[n + 1];
    float o0 = msg2[(size_t)n * 16 + 14];  // self + bias already folded
    float o1 = msg2[(size_t)n * 16 + 15];
    float ax[7], ay[7];
#pragma unroll
    for (int k = 0; k < 7; ++k) { ax[k] = NEGI; ay[k] = NEGI; }
    for (int p = st; p < en; ++p) {
        int pk = packed[p];
        int r = pk >> 17;
        const float2 f = *(const float2*)(msg2 + (size_t)(pk & SRC_MASK) * 16 + (r << 1));
#pragma unroll
        for (int k = 0; k < 7; ++k) {
            ax[k] = fmaxf(ax[k], (r == k) ? f.x : NEGI);
            ay[k] = fmaxf(ay[k], (r == k) ? f.y : NEGI);
        }
    }
#pragma unroll
    for (int k = 0; k < 7; ++k) {
        o0 += (ax[k] > NEGTEST) ? ax[k] : 0.f;
        o1 += (ay[k] > NEGTEST) ? ay[k] : 0.f;
    }
    out[(size_t)n * OUT_CH + 0] = o0;
    out[(size_t)n * OUT_CH + 1] = o1;
}

extern "C" void kernel_launch(void* const* d_in, const int* in_sizes, int n_in,
                              void* d_out, int out_size, void* d_ws, size_t ws_size,
                              hipStream_t stream)
{
    const float* x      = (const float*)d_in[0];
    const int*   ei     = (const int*)d_in[1];
    const int*   et     = (const int*)d_in[2];
    const float* W1     = (const float*)d_in[3];
    const float* root1  = (const float*)d_in[4];
    const float* bias1  = (const float*)d_in[5];
    const float* comp2  = (const float*)d_in[6];
    const float* basis2 = (const float*)d_in[7];
    const float* root2  = (const float*)d_in[8];
    const float* bias2  = (const float*)d_in[9];
    float* out = (float*)d_out;

    // workspace carve-up (~127 MB)
    char* ws = (char*)d_ws;
    size_t o = 0;
    auto carve = [&](size_t bytes) { char* p = ws + o; o += (bytes + 255) & ~(size_t)255; return p; };
    int*    deg    = (int*)carve(sizeof(int) * N_NODES);
    int*    off    = (int*)carve(sizeof(int) * (N_NODES + 1));
    int*    cursor = (int*)carve(sizeof(int) * (N_NODES + 1));
    int*    sums   = (int*)carve(sizeof(int) * 128);
    int*    packed = (int*)carve(sizeof(int) * N_EDGESV);
    __half* msg1   = (__half*)carve(sizeof(__half) * (size_t)N_NODES * N_REL * HID_CH); // 89.6 MB
    float*  hroot  = (float*)carve(sizeof(float) * (size_t)N_NODES * HID_CH);           // 25.6 MB
    float*  msg2   = (float*)carve(sizeof(float) * (size_t)N_NODES * 16);               //  6.4 MB

    // ---- CSR build ----
    hipMemsetAsync(deg, 0, sizeof(int) * N_NODES, stream);
    hist_kernel<<<(N_EDGESV + 255) / 256, 256, 0, stream>>>(ei, deg);
    scan1_kernel<<<NCHUNKS, 256, 0, stream>>>(deg, off, sums);
    scan2_kernel<<<1, 128, 0, stream>>>(sums);
    scan3_kernel<<<(N_NODES + 255) / 256, 256, 0, stream>>>(off, sums, cursor);
    scatter_kernel<<<(N_EDGESV + 255) / 256, 256, 0, stream>>>(ei, et, cursor, packed);

    // ---- dense precomputes ----
    rootmm_kernel<<<1024, 256, 0, stream>>>(x, root1, bias1, hroot);
    pre1_kernel<<<2048, 256, 0, stream>>>(x, W1, msg1);

    // ---- layer 1 aggregation (+ fused layer-2 message build) ----
    agg1_kernel<<<(N_NODES + 3) / 4, 256, 0, stream>>>(msg1, hroot, off, packed,
                                                       comp2, basis2, root2, bias2, msg2);

    // ---- layer 2 aggregation ----
    agg2_kernel<<<(N_NODES + 255) / 256, 256, 0, stream>>>(msg2, off, packed, out);
}